// Round 2
// baseline (46.012 us; speedup 1.0000x reference)
//
#include <hip/hip_runtime.h>

// MetaSR scale-4 on 64x64x64 feat. Exact-in-fp32 reduction: iy=y>>2,
// rel0=(y&3)*0.25, rel1=(x&3)*0.25, r_rev=0.25 -> only 16 distinct MLP
// inputs. Stage 1: 16 MLP evals -> pred_w[16][576][4]. Stage 2: per-subpixel
// 3x3x64->3 conv with feat tile in LDS and pred_w via scalar (s_load) path.

#define NOUT 1728
#define NC9  576

// ---------------- Kernel 1: pred_w[16][576][4] -----------------------------
// grid 432 = 16 s * 27 chunks of 64 outputs; block 256 = 64 outputs * 4 Ksplit
__global__ __launch_bounds__(256) void k_predw(
    const float* __restrict__ w1, const float* __restrict__ b1,
    const float* __restrict__ w2, const float* __restrict__ b2,
    float* __restrict__ predw)
{
    __shared__ float h[256];
    __shared__ float red[256];
    const int tid   = threadIdx.x;
    const int s     = blockIdx.x / 27;
    const int chunk = blockIdx.x - s * 27;

    const float rel0 = (float)(s >> 2) * 0.25f;
    const float rel1 = (float)(s & 3) * 0.25f;

    // h = relu(mlp_in @ w1 + b1), one element per thread
    float pre = fmaf(w1[tid], rel0,
                fmaf(w1[256 + tid], rel1,
                fmaf(w1[512 + tid], 0.25f, b1[tid])));
    h[tid] = fmaxf(pre, 0.0f);
    __syncthreads();

    const int olocal = tid & 63;
    const int q      = tid >> 6;           // K-quarter
    const int o      = chunk * 64 + olocal;
    const float* w2c = w2 + q * 64 * NOUT + o;
    const float* hq  = h + q * 64;

    float acc = 0.0f;
    #pragma unroll 8
    for (int j = 0; j < 64; ++j)
        acc = fmaf(hq[j], w2c[j * NOUT], acc);
    red[tid] = acc;
    __syncthreads();

    if (tid < 64) {
        const int oo = chunk * 64 + tid;
        float a = red[tid] + red[tid + 64] + red[tid + 128] + red[tid + 192]
                + b2[oo];
        const int c9 = oo / 3;
        const int k  = oo - c9 * 3;
        predw[(s * NC9 + c9) * 4 + k] = a;   // pad lane unused
    }
}

// ---------------- Kernel 2: conv 3x3x64 -> 3 per subpixel ------------------
// grid 1024 = 16 s * 64 cell-rows; block 256 = 4 waves (16ch each) * 64 cells
__global__ __launch_bounds__(256) void k_conv(
    const float* __restrict__ feat, const float* __restrict__ predw,
    float* __restrict__ out)
{
    __shared__ float ftile[3 * 64 * 64];   // [row3][c][x], zero-padded rows
    __shared__ float red[4 * 64 * 3];      // [wave][cell][rgb]

    const int tid = threadIdx.x;
    const int s   = blockIdx.x >> 6;
    const int r   = blockIdx.x & 63;       // LR row

    // stage feat rows r-1..r+1 (zeros outside)
    for (int i = tid; i < 3 * 64 * 64; i += 256) {
        const int row3 = i >> 12;          // 0..2
        const int rem  = i & 4095;         // c*64 + x
        const int ry   = r + row3 - 1;
        float v = 0.0f;
        if ((unsigned)ry < 64u)
            v = feat[(rem >> 6) * 4096 + ry * 64 + (rem & 63)];
        ftile[i] = v;
    }
    __syncthreads();

    const int lane = tid & 63;                                   // cx
    const int wq   = __builtin_amdgcn_readfirstlane(tid >> 6);   // ch quarter
    const float4* pws = (const float4*)predw + s * NC9 + wq * 16 * 9;

    float a0 = 0.f, a1 = 0.f, a2 = 0.f;

    #pragma unroll 4
    for (int cc = 0; cc < 16; ++cc) {
        const int c = wq * 16 + cc;
        const float*  fr = ftile + c * 64;     // + row3*4096 + rx
        const float4* pt = pws + cc * 9;
        #pragma unroll
        for (int t = 0; t < 9; ++t) {
            const int tr = t / 3, tc = t % 3;
            const int rx = lane + tc - 1;
            float v = 0.0f;
            if ((unsigned)rx < 64u) v = fr[tr * 4096 + rx];
            const float4 w = pt[t];            // wave-uniform -> s_load
            a0 = fmaf(v, w.x, a0);
            a1 = fmaf(v, w.y, a1);
            a2 = fmaf(v, w.z, a2);
        }
    }

    red[wq * 192 + lane * 3 + 0] = a0;
    red[wq * 192 + lane * 3 + 1] = a1;
    red[wq * 192 + lane * 3 + 2] = a2;
    __syncthreads();

    // 192 threads: cell = tid/3, k = tid%3
    if (tid < 192) {
        float v = red[tid] + red[192 + tid] + red[384 + tid] + red[576 + tid];
        const int cell = tid / 3;
        const int k    = tid - cell * 3;
        const int y = (r << 2) + (s >> 2);
        const int x = (cell << 2) + (s & 3);
        out[k * 65536 + y * 256 + x] = v;
    }
}

extern "C" void kernel_launch(void* const* d_in, const int* in_sizes, int n_in,
                              void* d_out, int out_size, void* d_ws, size_t ws_size,
                              hipStream_t stream) {
    const float* feat = (const float*)d_in[0];
    const float* w1   = (const float*)d_in[1];
    const float* b1   = (const float*)d_in[2];
    const float* w2   = (const float*)d_in[3];
    const float* b2   = (const float*)d_in[4];
    float* out   = (float*)d_out;
    float* predw = (float*)d_ws;   // 16*576*4 floats = 147456 B

    hipLaunchKernelGGL(k_predw, dim3(432), dim3(256), 0, stream,
                       w1, b1, w2, b2, predw);
    hipLaunchKernelGGL(k_conv, dim3(1024), dim3(256), 0, stream,
                       feat, predw, out);
}

// Round 3
// 22.080 us; speedup vs baseline: 2.0839x; 2.0839x over previous
//
#include <hip/hip_runtime.h>

// MetaSR scale-4, 64x64x64 feat -> 3x256x256. Exact-in-fp32: iy=y>>2,
// rel0=(y&3)*0.25, rel1=(x&3)*0.25, r_rev=0.25 -> 16 distinct MLP inputs.
// Stage 1: pred_w re-laid as predw[ct=576][48] (48 = s*3+k).
// Stage 2: GEMM view out[48][4096] = predw^T @ unfold[576][4096], output-split:
//   block = (LR row, subpixel-row sg), thread = cell, 12 outputs/thread,
//   8-wave K-split over channels + in-block tree reduce. No atomics.

#define NOUT 1728
#define NC9  576

// ---------------- Kernel 1: predw[576][48] ---------------------------------
// grid 432 = 16 s * 27 chunks of 64 outputs; block 256 = 64 outputs * 4 Ksplit
__global__ __launch_bounds__(256) void k_predw(
    const float* __restrict__ w1, const float* __restrict__ b1,
    const float* __restrict__ w2, const float* __restrict__ b2,
    float* __restrict__ predw)
{
    __shared__ float h[256];
    __shared__ float red[256];
    const int tid   = threadIdx.x;
    const int s     = blockIdx.x / 27;
    const int chunk = blockIdx.x - s * 27;

    const float rel0 = (float)(s >> 2) * 0.25f;
    const float rel1 = (float)(s & 3) * 0.25f;

    float pre = fmaf(w1[tid], rel0,
                fmaf(w1[256 + tid], rel1,
                fmaf(w1[512 + tid], 0.25f, b1[tid])));
    h[tid] = fmaxf(pre, 0.0f);
    __syncthreads();

    const int olocal = tid & 63;
    const int q      = tid >> 6;           // K-quarter
    const int o      = chunk * 64 + olocal;
    const float* w2c = w2 + q * 64 * NOUT + o;
    const float* hq  = h + q * 64;

    float acc = 0.0f;
    #pragma unroll 8
    for (int j = 0; j < 64; ++j)
        acc = fmaf(hq[j], w2c[j * NOUT], acc);
    red[tid] = acc;
    __syncthreads();

    if (tid < 64) {
        const int oo = chunk * 64 + tid;   // oo = ct*3 + k
        float a = red[tid] + red[tid + 64] + red[tid + 128] + red[tid + 192]
                + b2[oo];
        const int ct = oo / 3;
        const int k  = oo - ct * 3;
        predw[ct * 48 + s * 3 + k] = a;
    }
}

// ---------------- Kernel 2: conv, 12 outputs/thread ------------------------
// grid 256 = 4 sg * 64 rows; block 512 = 8 waves (8ch K-split) * 64 cells
__global__ __launch_bounds__(512) void k_conv(
    const float* __restrict__ feat, const float* __restrict__ predw,
    float* __restrict__ out)
{
    __shared__ float ftile[3 * 64 * 64];   // [tr][c][x], zero-padded rows
    __shared__ float red[4 * 12 * 64];     // [wave][j][lane]

    const int tid = threadIdx.x;
    const int sg  = blockIdx.x >> 6;       // subpixel row 0..3
    const int row = blockIdx.x & 63;       // LR row

    for (int i = tid; i < 3 * 64 * 64; i += 512) {
        const int tr  = i >> 12;
        const int rem = i & 4095;          // c*64 + x
        const int ry  = row + tr - 1;
        float v = 0.0f;
        if ((unsigned)ry < 64u)
            v = feat[(rem >> 6) * 4096 + ry * 64 + (rem & 63)];
        ftile[i] = v;
    }
    __syncthreads();

    const int lane = tid & 63;                                   // cx
    const int wq   = __builtin_amdgcn_readfirstlane(tid >> 6);   // 0..7
    const float* pwb = predw + sg * 12;

    float acc[12];
    #pragma unroll
    for (int j = 0; j < 12; ++j) acc[j] = 0.0f;

    int   xo[3];
    float xm[3];
    #pragma unroll
    for (int tc = 0; tc < 3; ++tc) {
        const int rx = lane + tc - 1;
        xm[tc] = ((unsigned)rx < 64u) ? 1.0f : 0.0f;
        xo[tc] = rx < 0 ? 0 : (rx > 63 ? 63 : rx);
    }

    #pragma unroll 2
    for (int cc = 0; cc < 8; ++cc) {
        const int c = wq * 8 + cc;
        const float* fb = ftile + c * 64;
        const int ctb = c * 9;
        #pragma unroll
        for (int tr = 0; tr < 3; ++tr) {
            #pragma unroll
            for (int tc = 0; tc < 3; ++tc) {
                const float v = fb[tr * 4096 + xo[tc]] * xm[tc];
                const float* pw = pwb + (ctb + tr * 3 + tc) * 48;  // uniform
                #pragma unroll
                for (int j = 0; j < 12; ++j)
                    acc[j] = fmaf(v, pw[j], acc[j]);
            }
        }
    }

    // tree reduce 8 waves -> wave 0
    for (int half = 4; half >= 1; half >>= 1) {
        if (wq >= half && wq < 2 * half) {
            #pragma unroll
            for (int j = 0; j < 12; ++j)
                red[(wq - half) * 768 + j * 64 + lane] = acc[j];
        }
        __syncthreads();
        if (wq < half) {
            #pragma unroll
            for (int j = 0; j < 12; ++j)
                acc[j] += red[wq * 768 + j * 64 + lane];
        }
        __syncthreads();
    }

    if (wq == 0) {
        const int y = (row << 2) + sg;
        #pragma unroll
        for (int j = 0; j < 12; ++j) {
            const int i = j / 3, k = j - i * 3;
            out[k * 65536 + y * 256 + (lane << 2) + i] = acc[j];
        }
    }
}

extern "C" void kernel_launch(void* const* d_in, const int* in_sizes, int n_in,
                              void* d_out, int out_size, void* d_ws, size_t ws_size,
                              hipStream_t stream) {
    const float* feat = (const float*)d_in[0];
    const float* w1   = (const float*)d_in[1];
    const float* b1   = (const float*)d_in[2];
    const float* w2   = (const float*)d_in[3];
    const float* b2   = (const float*)d_in[4];
    float* out   = (float*)d_out;
    float* predw = (float*)d_ws;   // 576*48 floats = 110592 B

    hipLaunchKernelGGL(k_predw, dim3(432), dim3(256), 0, stream,
                       w1, b1, w2, b2, predw);
    hipLaunchKernelGGL(k_conv, dim3(256), dim3(512), 0, stream,
                       feat, predw, out);
}

// Round 4
// 20.647 us; speedup vs baseline: 2.2285x; 1.0694x over previous
//
#include <hip/hip_runtime.h>

// MetaSR scale-4, 64x64x64 feat -> 3x256x256. Exact-in-fp32: iy=y>>2,
// rel0=(y&3)*0.25, rel1=(x&3)*0.25, r_rev=0.25 -> 16 distinct MLP inputs.
// Stage 1: predw2[sg][ct][12] (12 = (s&3)*3 + rgb), sg = s>>2.
// Stage 2: conv. Three independent operand streams, no cross-queue stalls:
//   feat via per-lane coalesced VMEM (vmcnt), pw via uniform SMEM s_load
//   batches (lgkmcnt, no DS in loop), accum in VGPRs. 8-wave K-split +
//   LDS tree reduce + float4 store transpose.

#define NOUT 1728

// ---------------- Kernel 1: predw2[4][576][12] ------------------------------
// grid 432 = 16 s * 27 chunks of 64 outputs; block 256 = 64 outputs * 4 Ksplit
__global__ __launch_bounds__(256) void k_predw(
    const float* __restrict__ w1, const float* __restrict__ b1,
    const float* __restrict__ w2, const float* __restrict__ b2,
    float* __restrict__ predw)
{
    __shared__ float h[256];
    __shared__ float red[256];
    const int tid   = threadIdx.x;
    const int s     = blockIdx.x / 27;
    const int chunk = blockIdx.x - s * 27;

    const float rel0 = (float)(s >> 2) * 0.25f;
    const float rel1 = (float)(s & 3) * 0.25f;

    float pre = fmaf(w1[tid], rel0,
                fmaf(w1[256 + tid], rel1,
                fmaf(w1[512 + tid], 0.25f, b1[tid])));
    h[tid] = fmaxf(pre, 0.0f);
    __syncthreads();

    const int olocal = tid & 63;
    const int q      = tid >> 6;           // K-quarter
    const int o      = chunk * 64 + olocal;
    const float* w2c = w2 + q * 64 * NOUT + o;
    const float* hq  = h + q * 64;

    float acc = 0.0f;
    #pragma unroll 8
    for (int j = 0; j < 64; ++j)
        acc = fmaf(hq[j], w2c[j * NOUT], acc);
    red[tid] = acc;
    __syncthreads();

    if (tid < 64) {
        const int oo = chunk * 64 + tid;   // oo = ct*3 + k
        float a = red[tid] + red[tid + 64] + red[tid + 128] + red[tid + 192]
                + b2[oo];
        const int ct = oo / 3;
        const int k  = oo - ct * 3;
        predw[((s >> 2) * 576 + ct) * 12 + (s & 3) * 3 + k] = a;
    }
}

// ---------------- Kernel 2: conv 3x3x64 -> 12 outputs/thread ----------------
// grid 256 = 4 sg * 64 rows; block 512 = 8 waves (8ch K-split) * 64 cells
__global__ __launch_bounds__(512) void k_conv(
    const float* __restrict__ feat, const float* __restrict__ predw,
    float* __restrict__ out)
{
    __shared__ float red[4 * 768];         // reduce + store-transpose buffer

    const int tid  = threadIdx.x;
    const int sg   = blockIdx.x >> 6;      // subpixel row 0..3
    const int row  = blockIdx.x & 63;      // LR row
    const int lane = tid & 63;             // cx
    const int wq   = __builtin_amdgcn_readfirstlane(tid >> 6);  // ch octant

    // clamped offsets + masks (no branches, no OOB reads)
    int   xoff[3];
    int   yoff[3];
    float m[9];
    #pragma unroll
    for (int tc = 0; tc < 3; ++tc) {
        const int rx = lane + tc - 1;
        const float mx = ((unsigned)rx < 64u) ? 1.0f : 0.0f;
        xoff[tc] = rx < 0 ? 0 : (rx > 63 ? 63 : rx);
        #pragma unroll
        for (int tr = 0; tr < 3; ++tr) {
            const int ry = row + tr - 1;
            m[tr * 3 + tc] = ((unsigned)ry < 64u) ? mx : 0.0f;
        }
    }
    #pragma unroll
    for (int tr = 0; tr < 3; ++tr) {
        const int ry = row + tr - 1;
        yoff[tr] = (ry < 0 ? 0 : (ry > 63 ? 63 : ry)) << 6;
    }

    const float* pwb = predw + (sg * 576 + wq * 72) * 12;  // wave-uniform

    float acc[12];
    #pragma unroll
    for (int j = 0; j < 12; ++j) acc[j] = 0.0f;

    #pragma unroll
    for (int cc = 0; cc < 8; ++cc) {
        const float* fc = feat + ((wq * 8 + cc) << 12);
        float f[9];
        #pragma unroll
        for (int tr = 0; tr < 3; ++tr)
            #pragma unroll
            for (int tc = 0; tc < 3; ++tc)
                f[tr * 3 + tc] = fc[yoff[tr] + xoff[tc]] * m[tr * 3 + tc];

        const float* pwc = pwb + cc * 108;  // 108 consecutive uniform floats
        #pragma unroll
        for (int t = 0; t < 9; ++t) {
            #pragma unroll
            for (int j = 0; j < 12; ++j)
                acc[j] = fmaf(f[t], pwc[t * 12 + j], acc[j]);
        }
    }

    // tree reduce 8 waves -> wave 0
    for (int half = 4; half >= 1; half >>= 1) {
        if (wq >= half && wq < 2 * half) {
            #pragma unroll
            for (int j = 0; j < 12; ++j)
                red[(wq - half) * 768 + j * 64 + lane] = acc[j];
        }
        __syncthreads();
        if (wq < half) {
            #pragma unroll
            for (int j = 0; j < 12; ++j)
                acc[j] += red[wq * 768 + j * 64 + lane];
        }
        __syncthreads();
    }

    // store transpose: wave0 regs -> LDS -> float4 coalesced stores
    if (wq == 0) {
        #pragma unroll
        for (int j = 0; j < 12; ++j)
            red[j * 64 + lane] = acc[j];
    }
    __syncthreads();
    if (tid < 192) {
        const int k  = tid >> 6;           // rgb
        const int x4 = tid & 63;           // LR cell x
        const int y  = (row << 2) + sg;
        float4 v;
        v.x = red[(0 * 3 + k) * 64 + x4];
        v.y = red[(1 * 3 + k) * 64 + x4];
        v.z = red[(2 * 3 + k) * 64 + x4];
        v.w = red[(3 * 3 + k) * 64 + x4];
        *(float4*)(out + k * 65536 + y * 256 + (x4 << 2)) = v;
    }
}

extern "C" void kernel_launch(void* const* d_in, const int* in_sizes, int n_in,
                              void* d_out, int out_size, void* d_ws, size_t ws_size,
                              hipStream_t stream) {
    const float* feat = (const float*)d_in[0];
    const float* w1   = (const float*)d_in[1];
    const float* b1   = (const float*)d_in[2];
    const float* w2   = (const float*)d_in[3];
    const float* b2   = (const float*)d_in[4];
    float* out   = (float*)d_out;
    float* predw = (float*)d_ws;   // 4*576*12 floats = 110592 B

    hipLaunchKernelGGL(k_predw, dim3(432), dim3(256), 0, stream,
                       w1, b1, w2, b2, predw);
    hipLaunchKernelGGL(k_conv, dim3(256), dim3(512), 0, stream,
                       feat, predw, out);
}

// Round 5
// 16.546 us; speedup vs baseline: 2.7809x; 1.2479x over previous
//
#include <hip/hip_runtime.h>

// MetaSR scale-4, 64x64x64 feat -> 3x256x256. Exact-in-fp32: iy=y>>2,
// rel0=(y&3)*0.25, rel1=(x&3)*0.25, r_rev=0.25 -> 16 distinct MLP inputs.
// Stage 1: predw[sg][ct][12]  (ct = c*9+tap, col j = (s&3)*3 + rgb).
// Stage 2: conv. pw slice staged in LDS, read as wave-uniform broadcast
//   ds_read_b128 (lgkm only); feat direct coalesced VMEM (vmcnt only);
//   block = 1024 thr = 16 waves x 4 channels -> 4 waves/SIMD; LDS tree
//   reduce 16->1; float4 store transpose.

#define NOUT 1728

// ---------------- Kernel 1: predw[4][576][12] ------------------------------
// grid 432 = 16 s * 27 chunks of 64 outputs; block 256 = 64 outputs * 4 Ksplit
__global__ __launch_bounds__(256) void k_predw(
    const float* __restrict__ w1, const float* __restrict__ b1,
    const float* __restrict__ w2, const float* __restrict__ b2,
    float* __restrict__ predw)
{
    __shared__ float h[256];
    __shared__ float red[256];
    const int tid   = threadIdx.x;
    const int s     = blockIdx.x / 27;
    const int chunk = blockIdx.x - s * 27;

    const float rel0 = (float)(s >> 2) * 0.25f;
    const float rel1 = (float)(s & 3) * 0.25f;

    float pre = fmaf(w1[tid], rel0,
                fmaf(w1[256 + tid], rel1,
                fmaf(w1[512 + tid], 0.25f, b1[tid])));
    h[tid] = fmaxf(pre, 0.0f);
    __syncthreads();

    const int olocal = tid & 63;
    const int q      = tid >> 6;           // K-quarter
    const int o      = chunk * 64 + olocal;
    const float* w2c = w2 + q * 64 * NOUT + o;
    const float* hq  = h + q * 64;

    float acc = 0.0f;
    #pragma unroll 8
    for (int j = 0; j < 64; ++j)
        acc = fmaf(hq[j], w2c[j * NOUT], acc);
    red[tid] = acc;
    __syncthreads();

    if (tid < 64) {
        const int oo = chunk * 64 + tid;   // oo = ct*3 + k
        float a = red[tid] + red[tid + 64] + red[tid + 128] + red[tid + 192]
                + b2[oo];
        const int ct = oo / 3;
        const int k  = oo - ct * 3;
        predw[((s >> 2) * 576 + ct) * 12 + (s & 3) * 3 + k] = a;
    }
}

// ---------------- Kernel 2: conv, 16 waves x 4 channels --------------------
// grid 256 = 4 sg * 64 rows; block 1024
__global__ __launch_bounds__(1024) void k_conv(
    const float* __restrict__ feat, const float* __restrict__ predw,
    float* __restrict__ out)
{
    __shared__ float pw[6912];             // [c][tap][12] for this sg
    __shared__ float red[8 * 768];         // reduce + store-transpose

    const int tid  = threadIdx.x;
    const int sg   = blockIdx.x >> 6;      // subpixel row 0..3
    const int row  = blockIdx.x & 63;      // LR row
    const int lane = tid & 63;             // cx
    const int wq   = __builtin_amdgcn_readfirstlane(tid >> 6);  // 0..15

    // stage pw sg-slice: 1728 float4, coalesced
    {
        const float4* src = (const float4*)(predw + sg * 6912);
        float4* dst = (float4*)pw;
        dst[tid] = src[tid];
        const int i2 = tid + 1024;
        if (i2 < 1728) dst[i2] = src[i2];
    }

    // clamped offsets + masks
    int   xoff[3];
    int   yoff[3];
    float m[9];
    #pragma unroll
    for (int tc = 0; tc < 3; ++tc) {
        const int rx = lane + tc - 1;
        const float mx = ((unsigned)rx < 64u) ? 1.0f : 0.0f;
        xoff[tc] = rx < 0 ? 0 : (rx > 63 ? 63 : rx);
        #pragma unroll
        for (int tr = 0; tr < 3; ++tr) {
            const int ry = row + tr - 1;
            m[tr * 3 + tc] = ((unsigned)ry < 64u) ? mx : 0.0f;
        }
    }
    #pragma unroll
    for (int tr = 0; tr < 3; ++tr) {
        const int ry = row + tr - 1;
        yoff[tr] = (ry < 0 ? 0 : (ry > 63 ? 63 : ry)) << 6;
    }
    __syncthreads();

    float a[12];
    #pragma unroll
    for (int j = 0; j < 12; ++j) a[j] = 0.0f;

    #pragma unroll
    for (int cc = 0; cc < 4; ++cc) {
        const int c = (wq << 2) | cc;
        const float* fc = feat + (c << 12);
        float f[9];
        #pragma unroll
        for (int tr = 0; tr < 3; ++tr)
            #pragma unroll
            for (int tc = 0; tc < 3; ++tc)
                f[tr * 3 + tc] = fc[yoff[tr] + xoff[tc]] * m[tr * 3 + tc];

        const float4* pwc = (const float4*)(pw + c * 108);  // wave-uniform
        #pragma unroll
        for (int t = 0; t < 9; ++t) {
            const float4 wA = pwc[t * 3 + 0];
            const float4 wB = pwc[t * 3 + 1];
            const float4 wC = pwc[t * 3 + 2];
            const float v = f[t];
            a[0]  = fmaf(v, wA.x, a[0]);
            a[1]  = fmaf(v, wA.y, a[1]);
            a[2]  = fmaf(v, wA.z, a[2]);
            a[3]  = fmaf(v, wA.w, a[3]);
            a[4]  = fmaf(v, wB.x, a[4]);
            a[5]  = fmaf(v, wB.y, a[5]);
            a[6]  = fmaf(v, wB.z, a[6]);
            a[7]  = fmaf(v, wB.w, a[7]);
            a[8]  = fmaf(v, wC.x, a[8]);
            a[9]  = fmaf(v, wC.y, a[9]);
            a[10] = fmaf(v, wC.z, a[10]);
            a[11] = fmaf(v, wC.w, a[11]);
        }
    }

    // tree reduce 16 waves -> wave 0
    for (int half = 8; half >= 1; half >>= 1) {
        if (wq >= half && wq < 2 * half) {
            #pragma unroll
            for (int j = 0; j < 12; ++j)
                red[(wq - half) * 768 + j * 64 + lane] = a[j];
        }
        __syncthreads();
        if (wq < half) {
            #pragma unroll
            for (int j = 0; j < 12; ++j)
                a[j] += red[wq * 768 + j * 64 + lane];
        }
        __syncthreads();
    }

    // store transpose: wave0 regs -> LDS -> float4 coalesced stores
    if (wq == 0) {
        #pragma unroll
        for (int j = 0; j < 12; ++j)
            red[j * 64 + lane] = a[j];
    }
    __syncthreads();
    if (tid < 192) {
        const int k  = tid >> 6;           // rgb
        const int x4 = tid & 63;           // LR cell x
        const int y  = (row << 2) + sg;
        float4 v;
        v.x = red[(0 * 3 + k) * 64 + x4];
        v.y = red[(1 * 3 + k) * 64 + x4];
        v.z = red[(2 * 3 + k) * 64 + x4];
        v.w = red[(3 * 3 + k) * 64 + x4];
        *(float4*)(out + k * 65536 + y * 256 + (x4 << 2)) = v;
    }
}

extern "C" void kernel_launch(void* const* d_in, const int* in_sizes, int n_in,
                              void* d_out, int out_size, void* d_ws, size_t ws_size,
                              hipStream_t stream) {
    const float* feat = (const float*)d_in[0];
    const float* w1   = (const float*)d_in[1];
    const float* b1   = (const float*)d_in[2];
    const float* w2   = (const float*)d_in[3];
    const float* b2   = (const float*)d_in[4];
    float* out   = (float*)d_out;
    float* predw = (float*)d_ws;   // 4*576*12 floats = 110592 B

    hipLaunchKernelGGL(k_predw, dim3(432), dim3(256), 0, stream,
                       w1, b1, w2, b2, predw);
    hipLaunchKernelGGL(k_conv, dim3(256), dim3(1024), 0, stream,
                       feat, predw, out);
}